// Round 1
// baseline (548.478 us; speedup 1.0000x reference)
//
#include <hip/hip_runtime.h>

constexpr int B = 8, T = 128, T_KEEP = 64, C = 128, F = 32, K = 64;
constexpr int CF = C * F;                    // 4096
constexpr int TOTAL = B * T_KEEP * C * F;    // 2,097,152 kept elements
constexpr int BLOCK = 256;

// Kernel 1: stable argsort of masktime (batch 0), take first t_keep indices.
// rank(t) = #{j : m[j] < m[t]  or  (m[j]==m[t] and j<t)}  -> stable ascending.
__global__ void keep_idx_kernel(const float* __restrict__ mask,
                                const int* __restrict__ t_keep_p,
                                int* __restrict__ keep) {
    __shared__ float m_s[T];
    int t = threadIdx.x;
    if (t < T) m_s[t] = mask[(size_t)t * CF];   // mask[0, t, 0, 0]
    __syncthreads();
    if (t < T) {
        float mt = m_s[t];
        int rank = 0;
        for (int j = 0; j < T; ++j) {
            float mj = m_s[j];
            rank += (mj < mt) || (mj == mt && j < t);
        }
        if (rank < t_keep_p[0]) keep[rank] = t;
    }
}

// Kernel 2: per kept element, argmin over K centers, write one-hot row of K.
// Each wave owns 64 consecutive elements -> 64*64 floats = 16KB contiguous
// output; stores are wave-transposed via __shfl so every float4 store is
// perfectly coalesced (lane l writes float4 at base + r*64 + l).
__global__ void __launch_bounds__(BLOCK) assign_onehot_kernel(
        const float* __restrict__ y,
        const float* __restrict__ centers,
        const int* __restrict__ keep,
        float* __restrict__ out) {
    __shared__ float sc[K];
    int tid = threadIdx.x;
    if (tid < K) sc[tid] = centers[tid];
    __syncthreads();

    int g = blockIdx.x * BLOCK + tid;        // kept-element index
    int lane = tid & 63;

    // decompose g -> (b, t, c, f); all dims are powers of two
    int f = g & (F - 1);
    int c = (g >> 5) & (C - 1);              // /F
    int t = (g >> 12) & (T_KEEP - 1);        // /(F*C)
    int b = g >> 18;                          // /(F*C*T_KEEP)

    // t is wave-uniform (changes every 4096 elems) -> keep[t] is an s_load
    int src = b * (T * CF) + keep[t] * CF + c * F + f;
    float x = y[src];

    // argmin over centers (first-occurrence on ties via strict <)
    int bi = 0;
    float bd = __builtin_inff();
    const float4* c4 = (const float4*)sc;
    #pragma unroll
    for (int k4 = 0; k4 < K / 4; ++k4) {
        float4 cv = c4[k4];
        float d;
        d = fabsf(x - cv.x); if (d < bd) { bd = d; bi = 4 * k4 + 0; }
        d = fabsf(x - cv.y); if (d < bd) { bd = d; bi = 4 * k4 + 1; }
        d = fabsf(x - cv.z); if (d < bd) { bd = d; bi = 4 * k4 + 2; }
        d = fabsf(x - cv.w); if (d < bd) { bd = d; bi = 4 * k4 + 3; }
    }

    // wave-transposed coalesced one-hot store
    int waveId = tid >> 6;
    int wbase = (blockIdx.x * BLOCK + waveId * 64) * (K / 4); // float4 index
    float4* out4 = (float4*)out;
    #pragma unroll
    for (int r = 0; r < 16; ++r) {
        int src_lane = r * 4 + (lane >> 4);  // which elem of this wave
        int bsrc = __shfl(bi, src_lane, 64);
        int k0 = (lane & 15) * 4;            // which 4 of the K outputs
        float4 v;
        v.x = (k0 + 0 == bsrc) ? 1.0f : 0.0f;
        v.y = (k0 + 1 == bsrc) ? 1.0f : 0.0f;
        v.z = (k0 + 2 == bsrc) ? 1.0f : 0.0f;
        v.w = (k0 + 3 == bsrc) ? 1.0f : 0.0f;
        out4[wbase + r * 64 + lane] = v;
    }
}

extern "C" void kernel_launch(void* const* d_in, const int* in_sizes, int n_in,
                              void* d_out, int out_size, void* d_ws, size_t ws_size,
                              hipStream_t stream) {
    const float* y       = (const float*)d_in[0];
    const float* mask    = (const float*)d_in[1];
    const float* centers = (const float*)d_in[2];
    const int*   t_keep  = (const int*)d_in[3];
    float* out = (float*)d_out;
    int* keep = (int*)d_ws;

    keep_idx_kernel<<<1, T, 0, stream>>>(mask, t_keep, keep);
    assign_onehot_kernel<<<TOTAL / BLOCK, BLOCK, 0, stream>>>(y, centers, keep, out);
}

// Round 4
// 544.483 us; speedup vs baseline: 1.0073x; 1.0073x over previous
//
#include <hip/hip_runtime.h>

constexpr int B = 8, T = 128, T_KEEP = 64, C = 128, F = 32, K = 64;
constexpr int CF = C * F;                    // 4096
constexpr int TOTAL = B * T_KEEP * C * F;    // 2,097,152 kept elements
constexpr int BLOCK = 256;
constexpr int EPT = 4;                       // elements per thread
constexpr int EPB = BLOCK * EPT;             // 1024 elements per block

typedef float vfloat4 __attribute__((ext_vector_type(4)));   // clang vector: OK for nontemporal builtin

// Single fused kernel.
// Each block: (a) computes its (block-uniform) kept time index via stable-rank
// over masktime in LDS, (b) argmin-assigns 1024 elements (4/thread), (c) emits
// one-hot rows via wave-transposed, fully-coalesced nontemporal float4 stores.
__global__ void __launch_bounds__(BLOCK) assign_onehot_fused(
        const float* __restrict__ y,
        const float* __restrict__ mask,
        const float* __restrict__ centers,
        float* __restrict__ out) {
    __shared__ float sc[K];
    __shared__ float m_s[T];
    __shared__ int keep_s;
    const int tid = threadIdx.x;

    if (tid < K) sc[tid] = centers[tid];
    if (tid < T) m_s[tid] = mask[(size_t)tid * CF];   // mask[0, t, 0, 0]
    __syncthreads();

    // stable ascending rank; this block covers kept-time index t_blk.
    // t changes every 4096 elems (EPB=1024 -> every 4 blocks) and repeats
    // per batch -> mask with T_KEEP-1.  (Round-3 bug: missing mask left
    // keep_s unset for t_blk>=128 -> wild reads -> abort.)
    const int t_blk = (blockIdx.x >> 2) & (T_KEEP - 1);
    if (tid < T) {
        float mt = m_s[tid];
        int rank = 0;
        #pragma unroll 8
        for (int j = 0; j < T; ++j) {
            float mj = m_s[j];
            rank += (mj < mt) || (mj == mt && j < tid);
        }
        if (rank == t_blk) keep_s = tid;   // rank is a permutation -> unique
    }
    __syncthreads();
    const int keep_t = keep_s;

    const int lane = tid & 63;
    const int wave = tid >> 6;
    const int wbase = blockIdx.x * EPB + wave * (EPT * 64);  // wave's first kept elem

    // source addresses: kept index g = wbase + e*64 + lane, contiguous in (c,f)
    const int b   = wbase >> 18;             // / (T_KEEP*C*F)
    const int cf0 = wbase & (CF - 1);
    const float* ysrc = y + (size_t)b * (T * CF) + (size_t)keep_t * CF + cf0;

    const float x0 = ysrc[lane];
    const float x1 = ysrc[64 + lane];
    const float x2 = ysrc[128 + lane];
    const float x3 = ysrc[192 + lane];

    int bi0 = 0, bi1 = 0, bi2 = 0, bi3 = 0;
    float bd0 = __builtin_inff(), bd1 = bd0, bd2 = bd0, bd3 = bd0;
    const float4* c4 = (const float4*)sc;
    #pragma unroll
    for (int k4 = 0; k4 < K / 4; ++k4) {
        float4 cv = c4[k4];
        float d;
        #define UPD(cvx, kk)                                            \
            d = fabsf(x0 - cvx); if (d < bd0) { bd0 = d; bi0 = kk; }    \
            d = fabsf(x1 - cvx); if (d < bd1) { bd1 = d; bi1 = kk; }    \
            d = fabsf(x2 - cvx); if (d < bd2) { bd2 = d; bi2 = kk; }    \
            d = fabsf(x3 - cvx); if (d < bd3) { bd3 = d; bi3 = kk; }
        UPD(cv.x, 4 * k4 + 0)
        UPD(cv.y, 4 * k4 + 1)
        UPD(cv.z, 4 * k4 + 2)
        UPD(cv.w, 4 * k4 + 3)
        #undef UPD
    }

    // wave-transposed coalesced one-hot stores: wave region = 256 rows x 64
    // floats = 64 KB contiguous. Store instr i4 covers rows i4*4+(lane>>4),
    // whose argmin lives in register e=i4>>4 of lane (i4&15)*4+(lane>>4).
    vfloat4* out4 = (vfloat4*)out;
    const size_t obase = (size_t)wbase * (K / 4);
    const int k0 = (lane & 15) * 4;
    const int sl_add = lane >> 4;
    #pragma unroll
    for (int i4 = 0; i4 < 64; ++i4) {
        const int e = i4 >> 4;                       // compile-time per iter
        int bsel = (e == 0) ? bi0 : (e == 1) ? bi1 : (e == 2) ? bi2 : bi3;
        int bsrc = __shfl(bsel, (i4 & 15) * 4 + sl_add, 64);
        vfloat4 v;
        v.x = (k0 + 0 == bsrc) ? 1.0f : 0.0f;
        v.y = (k0 + 1 == bsrc) ? 1.0f : 0.0f;
        v.z = (k0 + 2 == bsrc) ? 1.0f : 0.0f;
        v.w = (k0 + 3 == bsrc) ? 1.0f : 0.0f;
        __builtin_nontemporal_store(v, &out4[obase + i4 * 64 + lane]);
    }
}

extern "C" void kernel_launch(void* const* d_in, const int* in_sizes, int n_in,
                              void* d_out, int out_size, void* d_ws, size_t ws_size,
                              hipStream_t stream) {
    const float* y       = (const float*)d_in[0];
    const float* mask    = (const float*)d_in[1];
    const float* centers = (const float*)d_in[2];
    float* out = (float*)d_out;

    assign_onehot_fused<<<TOTAL / EPB, BLOCK, 0, stream>>>(y, mask, centers, out);
}